// Round 2
// baseline (564.350 us; speedup 1.0000x reference)
//
#include <hip/hip_runtime.h>

#define NND 50000
#define NE  800000
#define CF  128
#define NGR 512

typedef __bf16 bf16;
typedef __bf16 bf16x2 __attribute__((ext_vector_type(2)));
typedef __bf16 bf16x8 __attribute__((ext_vector_type(8)));
typedef float  f32x4  __attribute__((ext_vector_type(4)));

// ---- dtype-generic load/convert helpers ----
__device__ __forceinline__ float2 ld2(const bf16* p) {
  bf16x2 v = *(const bf16x2*)p;
  float2 r; r.x = (float)v.x; r.y = (float)v.y; return r;
}
__device__ __forceinline__ float2 ld2(const float* p) {
  return *(const float2*)p;
}
__device__ __forceinline__ bf16x8 ld8b(const bf16* p) { return *(const bf16x8*)p; }
__device__ __forceinline__ bf16x8 ld8b(const float* p) {
  f32x4 a = *(const f32x4*)p;
  f32x4 b = *(const f32x4*)(p + 4);
  bf16x8 r;
  r[0] = (bf16)a[0]; r[1] = (bf16)a[1]; r[2] = (bf16)a[2]; r[3] = (bf16)a[3];
  r[4] = (bf16)b[0]; r[5] = (bf16)b[1]; r[6] = (bf16)b[2]; r[7] = (bf16)b[3];
  return r;
}

// XOR-swizzled LDS index for B^T[n][k] (n:0..127, k:0..255 concat [wl;wr]).
__device__ __forceinline__ int swz(int n, int k) {
  return n * 256 + (((k >> 3) ^ (n & 31)) << 3) + (k & 7);
}

// ---------------- dtype detector ----------------
// bf16 N(0,1)-scale data: exponent field <= ~0x82. f32 data read as bf16:
// low halves carry mantissa bits in the exponent field -> >=0x90 w.h.p.
__global__ void detect_k(const unsigned short* __restrict__ xb, int* __restrict__ dt) {
  int bad = 0;
  for (int i = threadIdx.x; i < 2048; i += 256) {
    int e = (xb[i] >> 7) & 0xFF;
    if (e >= 0x90) bad = 1;
  }
  if (bad) atomicOr(dt, 1);  // 1 = float32 inputs, 0 = bf16 inputs
}

// ---------------- CSR build (dtype-free) ----------------
__global__ void count_k(const int* __restrict__ dst, int* __restrict__ cnt) {
  int e = blockIdx.x * 256 + threadIdx.x;
  if (e < NE) atomicAdd(&cnt[dst[e]], 1);
}

__global__ void scan1_k(const int* __restrict__ cnt, int* __restrict__ bsum) {
  __shared__ int sd[512];
  int t = threadIdx.x;
  int i = blockIdx.x * 512 + t;
  sd[t] = (i < NND) ? cnt[i] : 0;
  __syncthreads();
  for (int o = 256; o > 0; o >>= 1) {
    if (t < o) sd[t] += sd[t + o];
    __syncthreads();
  }
  if (t == 0) bsum[blockIdx.x] = sd[0];
}

__global__ void scan2_k(int* __restrict__ bsum, int* __restrict__ off) {
  __shared__ int sd[128];
  int t = threadIdx.x;
  int v = (t < 98) ? bsum[t] : 0;
  sd[t] = v;
  __syncthreads();
  for (int o = 1; o < 128; o <<= 1) {
    int u = (t >= o) ? sd[t - o] : 0;
    __syncthreads();
    sd[t] += u;
    __syncthreads();
  }
  if (t < 98) bsum[t] = sd[t] - v;  // exclusive block offsets
  if (t == 0) off[NND] = NE;
}

__global__ void scan3_k(const int* __restrict__ cnt, const int* __restrict__ bsum,
                        int* __restrict__ off) {
  __shared__ int sd[512];
  int t = threadIdx.x;
  int i = blockIdx.x * 512 + t;
  int v = (i < NND) ? cnt[i] : 0;
  sd[t] = v;
  __syncthreads();
  for (int o = 1; o < 512; o <<= 1) {
    int u = (t >= o) ? sd[t - o] : 0;
    __syncthreads();
    sd[t] += u;
    __syncthreads();
  }
  if (i < NND) off[i] = bsum[blockIdx.x] + sd[t] - v;
}

__global__ void fill_k(const int* __restrict__ src, const int* __restrict__ dst,
                       const int* __restrict__ off, int* __restrict__ cursor,
                       int* __restrict__ csr) {
  int e = blockIdx.x * 256 + threadIdx.x;
  if (e < NE) {
    int d = dst[e];
    int p = atomicAdd(&cursor[d], 1);
    csr[off[d] + p] = src[e];
  }
}

// ---------------- mean-aggregate from x (typed) ----------------
template <typename T>
__global__ __launch_bounds__(256) void aggx_k(const T* __restrict__ xin,
                                              const int* __restrict__ off,
                                              const int* __restrict__ csr,
                                              bf16* __restrict__ aggout,
                                              const int* __restrict__ dt, int want) {
  if (*dt != want) return;
  int wid  = (blockIdx.x * 256 + threadIdx.x) >> 6;
  int lane = threadIdx.x & 63;
  if (wid >= NND) return;
  int e0 = off[wid], e1 = off[wid + 1];
  float a0 = 0.f, a1 = 0.f;
  int e = e0;
  for (; e + 4 <= e1; e += 4) {
    int s0 = csr[e], s1 = csr[e + 1], s2 = csr[e + 2], s3 = csr[e + 3];
    float2 v0 = ld2(xin + s0 * 128 + 2 * lane);
    float2 v1 = ld2(xin + s1 * 128 + 2 * lane);
    float2 v2 = ld2(xin + s2 * 128 + 2 * lane);
    float2 v3 = ld2(xin + s3 * 128 + 2 * lane);
    a0 += v0.x + v1.x + v2.x + v3.x;
    a1 += v0.y + v1.y + v2.y + v3.y;
  }
  for (; e < e1; e++) {
    float2 v = ld2(xin + csr[e] * 128 + 2 * lane);
    a0 += v.x; a1 += v.y;
  }
  float inv = 1.0f / fmaxf((float)(e1 - e0), 1.0f);
  bf16x2 o;
  o.x = (bf16)(a0 * inv);
  o.y = (bf16)(a1 * inv);
  ((bf16x2*)aggout)[wid * 64 + lane] = o;
}

// mean-aggregate from internal bf16 h (runs in both dtype paths)
__global__ __launch_bounds__(256) void aggh_k(const bf16* __restrict__ xin,
                                              const int* __restrict__ off,
                                              const int* __restrict__ csr,
                                              bf16* __restrict__ aggout) {
  int wid  = (blockIdx.x * 256 + threadIdx.x) >> 6;
  int lane = threadIdx.x & 63;
  if (wid >= NND) return;
  int e0 = off[wid], e1 = off[wid + 1];
  const bf16x2* xp = (const bf16x2*)xin;
  float a0 = 0.f, a1 = 0.f;
  int e = e0;
  for (; e + 4 <= e1; e += 4) {
    int s0 = csr[e], s1 = csr[e + 1], s2 = csr[e + 2], s3 = csr[e + 3];
    bf16x2 v0 = xp[s0 * 64 + lane];
    bf16x2 v1 = xp[s1 * 64 + lane];
    bf16x2 v2 = xp[s2 * 64 + lane];
    bf16x2 v3 = xp[s3 * 64 + lane];
    a0 += (float)v0.x + (float)v1.x + (float)v2.x + (float)v3.x;
    a1 += (float)v0.y + (float)v1.y + (float)v2.y + (float)v3.y;
  }
  for (; e < e1; e++) {
    bf16x2 v = xp[csr[e] * 64 + lane];
    a0 += (float)v.x; a1 += (float)v.y;
  }
  float inv = 1.0f / fmaxf((float)(e1 - e0), 1.0f);
  bf16x2 o;
  o.x = (bf16)(a0 * inv);
  o.y = (bf16)(a1 * inv);
  ((bf16x2*)aggout)[wid * 64 + lane] = o;
}

// ---------------- fused [agg|prev] @ [wl;wr] + b, ReLU, (+prev), LayerNorm ----------------
// T = harness float dtype (weights), TP = prev/residual dtype, TO = output dtype.
// MFMA 16x16x32 bf16. A: A[m=lane&15][k=(lane>>4)*8+j]; B: B[k=(lane>>4)*8+j][n=lane&15];
// C/D: col=lane&15(+16t), row=(lane>>4)*4+reg.
template <typename T, typename TP, typename TO>
__global__ __launch_bounds__(256, 2) void gemm_k(
    const bf16* __restrict__ aggp, const TP* __restrict__ prev,
    const T* __restrict__ wl, const T* __restrict__ wr,
    const T* __restrict__ bias, const T* __restrict__ gamma,
    const T* __restrict__ beta, TO* __restrict__ outp, int addres,
    const int* __restrict__ dt, int want) {
  if (*dt != want) return;
  __shared__ bf16 bt[128 * 256];  // 64KB: B^T swizzled, [wl;wr] fused (K=256)
  int tid = threadIdx.x;
  for (int e = tid; e < 128 * 64; e += 256) {
    int k  = e >> 6;
    int n2 = (e & 63) << 1;
    {
      float2 v = ld2(wl + k * 128 + n2);
      bt[swz(n2, k)]     = (bf16)v.x;
      bt[swz(n2 + 1, k)] = (bf16)v.y;
    }
    {
      float2 v = ld2(wr + k * 128 + n2);
      bt[swz(n2, k + 128)]     = (bf16)v.x;
      bt[swz(n2 + 1, k + 128)] = (bf16)v.y;
    }
  }
  __syncthreads();

  int wave = tid >> 6, lane = tid & 63;
  int q = lane >> 4, r = lane & 15;
  int rowbase = blockIdx.x * 64 + wave * 16;
  int arow = rowbase + r;
  if (arow >= NND) arow = NND - 1;  // clamp: OOB rows computed but never stored

  f32x4 acc[8] = {};

#pragma unroll
  for (int kk = 0; kk < 8; kk++) {
    int kof = kk * 32 + q * 8;
    bf16x8 afrag;
    if (kk < 4) afrag = ld8b(aggp + arow * 128 + kof);
    else        afrag = ld8b(prev + arow * 128 + (kof - 128));
#pragma unroll
    for (int t = 0; t < 8; t++) {
      int n = t * 16 + r;
      bf16x8 bfrag = *(const bf16x8*)&bt[n * 256 + (((kof >> 3) ^ (n & 31)) << 3)];
      acc[t] = __builtin_amdgcn_mfma_f32_16x16x32_bf16(afrag, bfrag, acc[t], 0, 0, 0);
    }
  }

  float biasf[8], gf[8], bef[8];
#pragma unroll
  for (int t = 0; t < 8; t++) {
    int c = t * 16 + r;
    biasf[t] = (float)bias[c];
    gf[t]    = (float)gamma[c];
    bef[t]   = (float)beta[c];
  }

#pragma unroll
  for (int reg = 0; reg < 4; reg++) {
    int row = rowbase + q * 4 + reg;
    int rr  = (row < NND) ? row : (NND - 1);
    const TP* prow = prev + rr * 128;
    float vals[8];
    float s = 0.f, s2 = 0.f;
#pragma unroll
    for (int t = 0; t < 8; t++) {
      float v = acc[t][reg] + biasf[t];
      v = fmaxf(v, 0.f);
      if (addres) v += (float)prow[t * 16 + r];
      vals[t] = v;
      s += v;
      s2 += v * v;
    }
#pragma unroll
    for (int m = 1; m < 16; m <<= 1) {
      s  += __shfl_xor(s, m);
      s2 += __shfl_xor(s2, m);
    }
    float mean = s * (1.f / 128.f);
    float var  = fmaxf(s2 * (1.f / 128.f) - mean * mean, 0.f);
    float rstd = rsqrtf(var + 1e-5f);
    if (row < NND) {
      TO* orow = outp + row * 128;
#pragma unroll
      for (int t = 0; t < 8; t++)
        orow[t * 16 + r] = (TO)((vals[t] - mean) * rstd * gf[t] + bef[t]);
    }
  }
}

// ---------------- global mean pool ----------------
template <typename T>
__global__ __launch_bounds__(256) void pool_k(const T* __restrict__ h3,
                                              const int* __restrict__ batch,
                                              float* __restrict__ pool,
                                              float* __restrict__ pcnt,
                                              const int* __restrict__ dt, int want) {
  if (*dt != want) return;
  int wid  = (blockIdx.x * 256 + threadIdx.x) >> 6;
  int lane = threadIdx.x & 63;
  if (wid >= NND) return;
  int g = batch[wid];
  float2 v = ld2(h3 + wid * 128 + 2 * lane);
  atomicAdd(&pool[g * 128 + 2 * lane],     v.x);
  atomicAdd(&pool[g * 128 + 2 * lane + 1], v.y);
  if (lane == 0) atomicAdd(&pcnt[g], 1.0f);
}

// ---------------- head: avg = pool/cnt; out = avg @ wc + bc ----------------
template <typename T>
__global__ void head_k(const float* __restrict__ pool, const float* __restrict__ pcnt,
                       const T* __restrict__ wc, const T* __restrict__ bc,
                       T* __restrict__ outv, T* __restrict__ avgv,
                       const int* __restrict__ dt, int want) {
  if (*dt != want) return;
  int g = blockIdx.x, f = threadIdx.x;
  float inv = 1.f / fmaxf(pcnt[g], 1.f);
  float a = pool[g * 128 + f] * inv;
  avgv[g * 128 + f] = (T)a;
  float p0 = a * (float)wc[f * 2 + 0];
  float p1 = a * (float)wc[f * 2 + 1];
  for (int m = 1; m < 64; m <<= 1) {
    p0 += __shfl_xor(p0, m);
    p1 += __shfl_xor(p1, m);
  }
  __shared__ float sp[4];
  if ((f & 63) == 0) {
    sp[(f >> 6) * 2]     = p0;
    sp[(f >> 6) * 2 + 1] = p1;
  }
  __syncthreads();
  if (f == 0) {
    outv[g * 2 + 0] = (T)(sp[0] + sp[2] + (float)bc[0]);
    outv[g * 2 + 1] = (T)(sp[1] + sp[3] + (float)bc[1]);
  }
}

extern "C" void kernel_launch(void* const* d_in, const int* in_sizes, int n_in,
                              void* d_out, int out_size, void* d_ws, size_t ws_size,
                              hipStream_t stream) {
  const int* ei    = (const int*)d_in[1];
  const int* batch = (const int*)d_in[2];
  const int* srcv = ei;
  const int* dstv = ei + NE;

  // both typed views of every float input
  const bf16*  xB = (const bf16*)d_in[0];   const float* xF = (const float*)d_in[0];
#define WB(i) (const bf16*)d_in[i]
#define WF(i) (const float*)d_in[i]

  char* base = (char*)d_ws;
  int*   cnt    = (int*)(base + 0);            // 200000  [zeroed]
  int*   cursor = (int*)(base + 200192);       // 200000  [zeroed]
  float* pool   = (float*)(base + 400384);     // 262144  [zeroed]
  float* pcnt   = (float*)(base + 662528);     // 2048    [zeroed]
  int*   dt     = (int*)(base + 664576);       // 4       [zeroed]
  int*   off    = (int*)(base + 665088);       // 200004
  int*   bsum   = (int*)(base + 865280);       // 512
  int*   csr    = (int*)(base + 865792);       // 3200000
  bf16*  agg    = (bf16*)(base + 4065792);     // 12.8 MB
  bf16*  h1     = (bf16*)(base + 16865792);    // 12.8 MB
  bf16*  h2     = (bf16*)(base + 29665792);    // 12.8 MB (end ~42.5 MB)

  bf16*  outB = (bf16*)d_out;   float* outF = (float*)d_out;
  bf16*  h3B  = outB + 1024;    float* h3F  = outF + 1024;
  bf16*  avB  = outB + 1024 + NND * CF;
  float* avF  = outF + 1024 + NND * CF;

  hipMemsetAsync(base, 0, 664832, stream);
  detect_k<<<1, 256, 0, stream>>>((const unsigned short*)d_in[0], dt);

  count_k<<<3125, 256, 0, stream>>>(dstv, cnt);
  scan1_k<<<98, 512, 0, stream>>>(cnt, bsum);
  scan2_k<<<1, 128, 0, stream>>>(bsum, off);
  scan3_k<<<98, 512, 0, stream>>>(cnt, bsum, off);
  fill_k<<<3125, 256, 0, stream>>>(srcv, dstv, off, cursor, csr);

  // layer 1
  aggx_k<bf16> <<<12500, 256, 0, stream>>>(xB, off, csr, agg, dt, 0);
  aggx_k<float><<<12500, 256, 0, stream>>>(xF, off, csr, agg, dt, 1);
  gemm_k<bf16, bf16, bf16>  <<<782, 256, 0, stream>>>(agg, xB, WB(3), WB(4), WB(5), WB(6), WB(7), h1, 0, dt, 0);
  gemm_k<float, float, bf16><<<782, 256, 0, stream>>>(agg, xF, WF(3), WF(4), WF(5), WF(6), WF(7), h1, 0, dt, 1);
  // layer 2
  aggh_k<<<12500, 256, 0, stream>>>(h1, off, csr, agg);
  gemm_k<bf16, bf16, bf16> <<<782, 256, 0, stream>>>(agg, h1, WB(8), WB(9), WB(10), WB(11), WB(12), h2, 1, dt, 0);
  gemm_k<float, bf16, bf16><<<782, 256, 0, stream>>>(agg, h1, WF(8), WF(9), WF(10), WF(11), WF(12), h2, 1, dt, 1);
  // layer 3
  aggh_k<<<12500, 256, 0, stream>>>(h2, off, csr, agg);
  gemm_k<bf16, bf16, bf16>  <<<782, 256, 0, stream>>>(agg, h2, WB(13), WB(14), WB(15), WB(16), WB(17), h3B, 1, dt, 0);
  gemm_k<float, bf16, float><<<782, 256, 0, stream>>>(agg, h2, WF(13), WF(14), WF(15), WF(16), WF(17), h3F, 1, dt, 1);
  // pool + head
  pool_k<bf16> <<<12500, 256, 0, stream>>>(h3B, batch, pool, pcnt, dt, 0);
  pool_k<float><<<12500, 256, 0, stream>>>(h3F, batch, pool, pcnt, dt, 1);
  head_k<bf16> <<<NGR, 128, 0, stream>>>(pool, pcnt, WB(18), WB(19), outB, avB, dt, 0);
  head_k<float><<<NGR, 128, 0, stream>>>(pool, pcnt, WF(18), WF(19), outF, avF, dt, 1);
#undef WB
#undef WF
}

// Round 3
// 450.744 us; speedup vs baseline: 1.2520x; 1.2520x over previous
//
#include <hip/hip_runtime.h>

#define NND 50000
#define NE  800000
#define CF  128
#define NGR 512

typedef __bf16 bf16;
typedef __bf16 bf16x2 __attribute__((ext_vector_type(2)));
typedef __bf16 bf16x8 __attribute__((ext_vector_type(8)));
typedef float  f32x4  __attribute__((ext_vector_type(4)));

struct F8 { float v[8]; };

// ---- dtype-generic load/convert helpers ----
__device__ __forceinline__ float2 ld2(const bf16* p) {
  bf16x2 v = *(const bf16x2*)p;
  float2 r; r.x = (float)v.x; r.y = (float)v.y; return r;
}
__device__ __forceinline__ float2 ld2(const float* p) { return *(const float2*)p; }

__device__ __forceinline__ F8 ld8f(const bf16* p) {
  bf16x8 v = *(const bf16x8*)p;
  F8 r;
#pragma unroll
  for (int j = 0; j < 8; j++) r.v[j] = (float)v[j];
  return r;
}
__device__ __forceinline__ F8 ld8f(const float* p) {
  f32x4 a = *(const f32x4*)p;
  f32x4 b = *(const f32x4*)(p + 4);
  F8 r;
#pragma unroll
  for (int j = 0; j < 4; j++) { r.v[j] = a[j]; r.v[4 + j] = b[j]; }
  return r;
}
__device__ __forceinline__ bf16x8 ld8b(const bf16* p) { return *(const bf16x8*)p; }
__device__ __forceinline__ bf16x8 ld8b(const float* p) {
  f32x4 a = *(const f32x4*)p;
  f32x4 b = *(const f32x4*)(p + 4);
  bf16x8 r;
  r[0] = (bf16)a[0]; r[1] = (bf16)a[1]; r[2] = (bf16)a[2]; r[3] = (bf16)a[3];
  r[4] = (bf16)b[0]; r[5] = (bf16)b[1]; r[6] = (bf16)b[2]; r[7] = (bf16)b[3];
  return r;
}

// XOR-swizzled LDS index for B^T[n][k] (n:0..127, k:0..255 concat [wl;wr]).
__device__ __forceinline__ int swz(int n, int k) {
  return n * 256 + (((k >> 3) ^ (n & 31)) << 3) + (k & 7);
}

// ---------------- dtype detector ----------------
__global__ void detect_k(const unsigned short* __restrict__ xb, int* __restrict__ dt) {
  int bad = 0;
  for (int i = threadIdx.x; i < 2048; i += 256) {
    int e = (xb[i] >> 7) & 0xFF;
    if (e >= 0x90) bad = 1;
  }
  if (bad) atomicOr(dt, 1);  // 1 = float32 inputs, 0 = bf16 inputs
}

// ---------------- CSR build ----------------
__global__ void count_k(const int* __restrict__ dst, int* __restrict__ cnt) {
  int e = blockIdx.x * 256 + threadIdx.x;
  if (e < NE) atomicAdd(&cnt[dst[e]], 1);
}

__global__ void scan1_k(const int* __restrict__ cnt, int* __restrict__ bsum) {
  __shared__ int sd[512];
  int t = threadIdx.x;
  int i = blockIdx.x * 512 + t;
  sd[t] = (i < NND) ? cnt[i] : 0;
  __syncthreads();
  for (int o = 256; o > 0; o >>= 1) {
    if (t < o) sd[t] += sd[t + o];
    __syncthreads();
  }
  if (t == 0) bsum[blockIdx.x] = sd[0];
}

__global__ void scan2_k(int* __restrict__ bsum, int* __restrict__ off) {
  __shared__ int sd[128];
  int t = threadIdx.x;
  int v = (t < 98) ? bsum[t] : 0;
  sd[t] = v;
  __syncthreads();
  for (int o = 1; o < 128; o <<= 1) {
    int u = (t >= o) ? sd[t - o] : 0;
    __syncthreads();
    sd[t] += u;
    __syncthreads();
  }
  if (t < 98) bsum[t] = sd[t] - v;
  if (t == 0) off[NND] = NE;
}

__global__ void scan3_k(const int* __restrict__ cnt, const int* __restrict__ bsum,
                        int* __restrict__ off) {
  __shared__ int sd[512];
  int t = threadIdx.x;
  int i = blockIdx.x * 512 + t;
  int v = (i < NND) ? cnt[i] : 0;
  sd[t] = v;
  __syncthreads();
  for (int o = 1; o < 512; o <<= 1) {
    int u = (t >= o) ? sd[t - o] : 0;
    __syncthreads();
    sd[t] += u;
    __syncthreads();
  }
  if (i < NND) off[i] = bsum[blockIdx.x] + sd[t] - v;
}

__global__ void fill_k(const int* __restrict__ src, const int* __restrict__ dst,
                       const int* __restrict__ off, int* __restrict__ cursor,
                       int* __restrict__ csr) {
  int e = blockIdx.x * 256 + threadIdx.x;
  if (e < NE) {
    int d = dst[e];
    int p = atomicAdd(&cursor[d], 1);
    csr[off[d] + p] = src[e];
  }
}

// ---------------- graph boundaries from sorted batch ----------------
__global__ void gb_k(const int* __restrict__ batch, int* __restrict__ gs) {
  int i = blockIdx.x * 256 + threadIdx.x;
  if (i >= NND) return;
  int b = batch[i];
  if (i == 0) {
    for (int g = 0; g <= b; g++) gs[g] = 0;
  } else {
    int pb = batch[i - 1];
    for (int g = pb + 1; g <= b; g++) gs[g] = i;
  }
  if (i == NND - 1) {
    for (int g = b + 1; g <= NGR; g++) gs[g] = NND;
  }
}

// ---------------- mean-aggregate: wave handles 1 node, 16B/lane, 4 rows/load ----------------
// want = -1: always run (internal bf16 h). Otherwise gate on dtype flag.
template <typename T>
__global__ __launch_bounds__(256) void agg_k(const T* __restrict__ xin,
                                             const int* __restrict__ off,
                                             const int* __restrict__ csr,
                                             bf16* __restrict__ aggout,
                                             const int* __restrict__ dt, int want) {
  if (want >= 0 && *dt != want) return;
  int wid  = (blockIdx.x * 256 + threadIdx.x) >> 6;
  int lane = threadIdx.x & 63;
  if (wid >= NND) return;
  int sub = lane >> 4;        // edge slot 0..3
  int c8  = (lane & 15) * 8;  // feature group
  int e0 = off[wid], e1 = off[wid + 1];
  float a[8] = {};
  for (int e = e0; e < e1; e += 4) {
    int idx = e + sub;
    int s   = csr[(idx < e1) ? idx : (e1 - 1)];
    float m = (idx < e1) ? 1.f : 0.f;
    F8 v = ld8f(xin + s * 128 + c8);
#pragma unroll
    for (int j = 0; j < 8; j++) a[j] += m * v.v[j];
  }
#pragma unroll
  for (int j = 0; j < 8; j++) {
    a[j] += __shfl_xor(a[j], 16);
    a[j] += __shfl_xor(a[j], 32);
  }
  if (sub == 0) {
    float inv = 1.0f / fmaxf((float)(e1 - e0), 1.0f);
    bf16x8 o;
#pragma unroll
    for (int j = 0; j < 8; j++) o[j] = (bf16)(a[j] * inv);
    *(bf16x8*)(aggout + wid * 128 + c8) = o;
  }
}

// ---------------- fused [agg|prev] @ [wl;wr] + b, ReLU, (+prev), LayerNorm ----------------
// Block = 256 thr (4 waves); block covers 256 rows, wave covers 64 rows (4 row-tiles of 16).
// B-frag reused across 4 MFMAs; weights staged once per block (196 blocks).
// MFMA 16x16x32: A[m=lane&15][k=q*8+j]; B[k=q*8+j][n=lane&15]; C/D col=lane&15, row=q*4+reg.
template <typename T, typename TP, typename TO>
__global__ __launch_bounds__(256, 1) void gemm_k(
    const bf16* __restrict__ aggp, const TP* __restrict__ prev,
    const T* __restrict__ wl, const T* __restrict__ wr,
    const T* __restrict__ bias, const T* __restrict__ gamma,
    const T* __restrict__ beta, TO* __restrict__ outp, int addres,
    const int* __restrict__ dt, int want) {
  if (*dt != want) return;
  __shared__ bf16 bt[128 * 256];  // 64KB: B^T swizzled, [wl;wr] fused (K=256)
  int tid = threadIdx.x;
  for (int e = tid; e < 128 * 64; e += 256) {
    int k  = e >> 6;
    int n2 = (e & 63) << 1;
    {
      float2 v = ld2(wl + k * 128 + n2);
      bt[swz(n2, k)]     = (bf16)v.x;
      bt[swz(n2 + 1, k)] = (bf16)v.y;
    }
    {
      float2 v = ld2(wr + k * 128 + n2);
      bt[swz(n2, k + 128)]     = (bf16)v.x;
      bt[swz(n2 + 1, k + 128)] = (bf16)v.y;
    }
  }
  __syncthreads();

  int wave = tid >> 6, lane = tid & 63;
  int q = lane >> 4, r = lane & 15;
  int wrow = blockIdx.x * 256 + wave * 64;

  int arow[4];
#pragma unroll
  for (int rt = 0; rt < 4; rt++) {
    int ar = wrow + rt * 16 + r;
    arow[rt] = (ar < NND) ? ar : (NND - 1);  // clamped; OOB rows never stored
  }

  f32x4 acc[4][8] = {};

#pragma unroll
  for (int kk = 0; kk < 8; kk++) {
    int kof = kk * 32 + q * 8;
    bf16x8 af[4];
#pragma unroll
    for (int rt = 0; rt < 4; rt++) {
      if (kk < 4) af[rt] = ld8b(aggp + arow[rt] * 128 + kof);
      else        af[rt] = ld8b(prev + arow[rt] * 128 + (kof - 128));
    }
#pragma unroll
    for (int t = 0; t < 8; t++) {
      int n = t * 16 + r;
      bf16x8 bfrag = *(const bf16x8*)&bt[n * 256 + (((kof >> 3) ^ (n & 31)) << 3)];
#pragma unroll
      for (int rt = 0; rt < 4; rt++)
        acc[rt][t] = __builtin_amdgcn_mfma_f32_16x16x32_bf16(af[rt], bfrag, acc[rt][t], 0, 0, 0);
    }
  }

  float biasf[8], gf[8], bef[8];
#pragma unroll
  for (int t = 0; t < 8; t++) {
    int c = t * 16 + r;
    biasf[t] = (float)bias[c];
    gf[t]    = (float)gamma[c];
    bef[t]   = (float)beta[c];
  }

#pragma unroll
  for (int rt = 0; rt < 4; rt++) {
#pragma unroll
    for (int reg = 0; reg < 4; reg++) {
      int row = wrow + rt * 16 + q * 4 + reg;
      int rr  = (row < NND) ? row : (NND - 1);
      const TP* prow = prev + rr * 128;
      float vals[8];
      float s = 0.f, s2 = 0.f;
#pragma unroll
      for (int t = 0; t < 8; t++) {
        float v = acc[rt][t][reg] + biasf[t];
        v = fmaxf(v, 0.f);
        if (addres) v += (float)prow[t * 16 + r];
        vals[t] = v;
        s += v;
        s2 += v * v;
      }
#pragma unroll
      for (int m = 1; m < 16; m <<= 1) {
        s  += __shfl_xor(s, m);
        s2 += __shfl_xor(s2, m);
      }
      float mean = s * (1.f / 128.f);
      float var  = fmaxf(s2 * (1.f / 128.f) - mean * mean, 0.f);
      float rstd = rsqrtf(var + 1e-5f);
      if (row < NND) {
        TO* orow = outp + row * 128;
#pragma unroll
        for (int t = 0; t < 8; t++)
          orow[t * 16 + r] = (TO)((vals[t] - mean) * rstd * gf[t] + bef[t]);
      }
    }
  }
}

// ---------------- fused mean-pool + head (sorted batch, no atomics) ----------------
template <typename TH, typename T>
__global__ __launch_bounds__(256) void poolhead_k(
    const TH* __restrict__ h3, const int* __restrict__ gs,
    const T* __restrict__ wc, const T* __restrict__ bc,
    T* __restrict__ outv, T* __restrict__ avgv,
    const int* __restrict__ dt, int want) {
  if (*dt != want) return;
  int g = blockIdx.x;
  int s = gs[g], epos = gs[g + 1];
  int tid = threadIdx.x;
  int wave = tid >> 6, lane = tid & 63;
  float a0 = 0.f, a1 = 0.f;
  for (int row = s + wave; row < epos; row += 4) {
    float2 v = ld2(h3 + row * 128 + 2 * lane);
    a0 += v.x; a1 += v.y;
  }
  __shared__ float red[4][128];
  red[wave][2 * lane]     = a0;
  red[wave][2 * lane + 1] = a1;
  __syncthreads();
  __shared__ float sp[4];
  if (tid < 128) {
    float t4  = red[0][tid] + red[1][tid] + red[2][tid] + red[3][tid];
    float inv = 1.f / fmaxf((float)(epos - s), 1.f);
    float avg = t4 * inv;
    avgv[g * 128 + tid] = (T)avg;
    float p0 = avg * (float)wc[tid * 2 + 0];
    float p1 = avg * (float)wc[tid * 2 + 1];
#pragma unroll
    for (int m = 1; m < 64; m <<= 1) {
      p0 += __shfl_xor(p0, m);
      p1 += __shfl_xor(p1, m);
    }
    if ((tid & 63) == 0) {
      sp[(tid >> 6) * 2]     = p0;
      sp[(tid >> 6) * 2 + 1] = p1;
    }
  }
  __syncthreads();
  if (tid == 0) {
    outv[g * 2 + 0] = (T)(sp[0] + sp[2] + (float)bc[0]);
    outv[g * 2 + 1] = (T)(sp[1] + sp[3] + (float)bc[1]);
  }
}

extern "C" void kernel_launch(void* const* d_in, const int* in_sizes, int n_in,
                              void* d_out, int out_size, void* d_ws, size_t ws_size,
                              hipStream_t stream) {
  const int* ei    = (const int*)d_in[1];
  const int* batch = (const int*)d_in[2];
  const int* srcv = ei;
  const int* dstv = ei + NE;

  const bf16*  xB = (const bf16*)d_in[0];   const float* xF = (const float*)d_in[0];
#define WB(i) (const bf16*)d_in[i]
#define WF(i) (const float*)d_in[i]

  char* base = (char*)d_ws;
  int*  cnt    = (int*)(base + 0);            // 200000  [zeroed]
  int*  cursor = (int*)(base + 200192);       // 200000  [zeroed]
  int*  dt     = (int*)(base + 400384);       // 4       [zeroed]
  int*  gs     = (int*)(base + 400512);       // 2052
  int*  off    = (int*)(base + 402688);       // 200004
  int*  bsum   = (int*)(base + 602752);       // 512
  int*  csr    = (int*)(base + 603264);       // 3200000
  bf16* agg    = (bf16*)(base + 3803264);     // 12.8 MB
  bf16* h1     = (bf16*)(base + 16603264);    // 12.8 MB
  bf16* h2     = (bf16*)(base + 29403264);    // 12.8 MB (end ~42.2 MB)

  bf16*  outB = (bf16*)d_out;   float* outF = (float*)d_out;
  bf16*  h3B  = outB + 1024;    float* h3F  = outF + 1024;
  bf16*  avB  = outB + 1024 + NND * CF;
  float* avF  = outF + 1024 + NND * CF;

  hipMemsetAsync(base, 0, 400512, stream);
  detect_k<<<1, 256, 0, stream>>>((const unsigned short*)d_in[0], dt);

  count_k<<<3125, 256, 0, stream>>>(dstv, cnt);
  scan1_k<<<98, 512, 0, stream>>>(cnt, bsum);
  scan2_k<<<1, 128, 0, stream>>>(bsum, off);
  scan3_k<<<98, 512, 0, stream>>>(cnt, bsum, off);
  fill_k<<<3125, 256, 0, stream>>>(srcv, dstv, off, cursor, csr);
  gb_k<<<196, 256, 0, stream>>>(batch, gs);

  // layer 1
  agg_k<bf16> <<<12500, 256, 0, stream>>>(xB, off, csr, agg, dt, 0);
  agg_k<float><<<12500, 256, 0, stream>>>(xF, off, csr, agg, dt, 1);
  gemm_k<bf16, bf16, bf16>  <<<196, 256, 0, stream>>>(agg, xB, WB(3), WB(4), WB(5), WB(6), WB(7), h1, 0, dt, 0);
  gemm_k<float, float, bf16><<<196, 256, 0, stream>>>(agg, xF, WF(3), WF(4), WF(5), WF(6), WF(7), h1, 0, dt, 1);
  // layer 2
  agg_k<bf16><<<12500, 256, 0, stream>>>(h1, off, csr, agg, dt, -1);
  gemm_k<bf16, bf16, bf16> <<<196, 256, 0, stream>>>(agg, h1, WB(8), WB(9), WB(10), WB(11), WB(12), h2, 1, dt, 0);
  gemm_k<float, bf16, bf16><<<196, 256, 0, stream>>>(agg, h1, WF(8), WF(9), WF(10), WF(11), WF(12), h2, 1, dt, 1);
  // layer 3
  agg_k<bf16><<<12500, 256, 0, stream>>>(h2, off, csr, agg, dt, -1);
  gemm_k<bf16, bf16, bf16>  <<<196, 256, 0, stream>>>(agg, h2, WB(13), WB(14), WB(15), WB(16), WB(17), h3B, 1, dt, 0);
  gemm_k<float, bf16, float><<<196, 256, 0, stream>>>(agg, h2, WF(13), WF(14), WF(15), WF(16), WF(17), h3F, 1, dt, 1);
  // pool + head (fused, atomic-free)
  poolhead_k<bf16, bf16>  <<<NGR, 256, 0, stream>>>(h3B, gs, WB(18), WB(19), outB, avB, dt, 0);
  poolhead_k<float, float><<<NGR, 256, 0, stream>>>(h3F, gs, WF(18), WF(19), outF, avF, dt, 1);
#undef WB
#undef WF
}

// Round 4
// 402.295 us; speedup vs baseline: 1.4028x; 1.1204x over previous
//
#include <hip/hip_runtime.h>

#define NND 50000
#define NE  800000
#define CF  128
#define NGR 512

typedef __bf16 bf16;
typedef __bf16 bf16x4 __attribute__((ext_vector_type(4)));
typedef __bf16 bf16x8 __attribute__((ext_vector_type(8)));
typedef float  f32x4  __attribute__((ext_vector_type(4)));

// XOR-swizzled LDS index for B^T[n][k] (n:0..127, k:0..255 concat [wl;wr]).
__device__ __forceinline__ int swz(int n, int k) {
  return n * 256 + (((k >> 3) ^ (n & 31)) << 3) + (k & 7);
}

// ---------------- fused x->bf16 convert + degree count ----------------
// grid 6250x256 = 1.6M threads; each converts 4 floats; first 800K also count.
__global__ __launch_bounds__(256) void convcount_k(const float* __restrict__ x,
                                                   bf16* __restrict__ xb,
                                                   const int* __restrict__ dst,
                                                   int* __restrict__ cnt) {
  int t = blockIdx.x * 256 + threadIdx.x;
  if (t < (NND * CF / 4)) {
    f32x4 v = ((const f32x4*)x)[t];
    bf16x4 o;
    o[0] = (bf16)v[0]; o[1] = (bf16)v[1]; o[2] = (bf16)v[2]; o[3] = (bf16)v[3];
    ((bf16x4*)xb)[t] = o;
  }
  if (t < NE) atomicAdd(&cnt[dst[t]], 1);
}

// ---------------- CSR build ----------------
__global__ void scan1_k(const int* __restrict__ cnt, int* __restrict__ bsum) {
  __shared__ int sd[512];
  int t = threadIdx.x;
  int i = blockIdx.x * 512 + t;
  sd[t] = (i < NND) ? cnt[i] : 0;
  __syncthreads();
  for (int o = 256; o > 0; o >>= 1) {
    if (t < o) sd[t] += sd[t + o];
    __syncthreads();
  }
  if (t == 0) bsum[blockIdx.x] = sd[0];
}

__global__ void scan2_k(int* __restrict__ bsum, int* __restrict__ off) {
  __shared__ int sd[128];
  int t = threadIdx.x;
  int v = (t < 98) ? bsum[t] : 0;
  sd[t] = v;
  __syncthreads();
  for (int o = 1; o < 128; o <<= 1) {
    int u = (t >= o) ? sd[t - o] : 0;
    __syncthreads();
    sd[t] += u;
    __syncthreads();
  }
  if (t < 98) bsum[t] = sd[t] - v;  // exclusive block offsets
  if (t == 0) off[NND] = NE;
}

__global__ void scan3_k(const int* __restrict__ cnt, const int* __restrict__ bsum,
                        int* __restrict__ off, int* __restrict__ cursor) {
  __shared__ int sd[512];
  int t = threadIdx.x;
  int i = blockIdx.x * 512 + t;
  int v = (i < NND) ? cnt[i] : 0;
  sd[t] = v;
  __syncthreads();
  for (int o = 1; o < 512; o <<= 1) {
    int u = (t >= o) ? sd[t - o] : 0;
    __syncthreads();
    sd[t] += u;
    __syncthreads();
  }
  if (i < NND) {
    int p = bsum[blockIdx.x] + sd[t] - v;
    off[i] = p;
    cursor[i] = p;  // fill uses cursor directly (absolute positions)
  }
}

__global__ void fill_k(const int* __restrict__ src, const int* __restrict__ dst,
                       int* __restrict__ cursor, int* __restrict__ csr) {
  int e = blockIdx.x * 256 + threadIdx.x;
  if (e < NE) {
    int p = atomicAdd(&cursor[dst[e]], 1);
    csr[p] = src[e];
  }
}

// ---------------- graph boundaries from sorted batch ----------------
__global__ void gb_k(const int* __restrict__ batch, int* __restrict__ gs) {
  int i = blockIdx.x * 256 + threadIdx.x;
  if (i >= NND) return;
  int b = batch[i];
  if (i == 0) {
    for (int g = 0; g <= b; g++) gs[g] = 0;
  } else {
    int pb = batch[i - 1];
    for (int g = pb + 1; g <= b; g++) gs[g] = i;
  }
  if (i == NND - 1) {
    for (int g = b + 1; g <= NGR; g++) gs[g] = NND;
  }
}

// ---------------- mean-aggregate: wave = 1 node; 16 lanes x 16B; 8 edges in flight ----
__global__ __launch_bounds__(256) void agg_k(const bf16* __restrict__ xin,
                                             const int* __restrict__ off,
                                             const int* __restrict__ csr,
                                             bf16* __restrict__ aggout) {
  int wid  = (blockIdx.x * 256 + threadIdx.x) >> 6;
  int lane = threadIdx.x & 63;
  if (wid >= NND) return;
  int sub = lane >> 4;        // edge slot 0..3
  int c8  = (lane & 15) * 8;  // feature group
  int e0 = off[wid], e1 = off[wid + 1];
  float a[8] = {};
  for (int e = e0; e < e1; e += 8) {
    int i0 = e + sub, i1 = e + 4 + sub;
    int s0 = csr[(i0 < e1) ? i0 : (e1 - 1)];
    int s1 = csr[(i1 < e1) ? i1 : (e1 - 1)];
    float m0 = (i0 < e1) ? 1.f : 0.f;
    float m1 = (i1 < e1) ? 1.f : 0.f;
    bf16x8 v0 = *(const bf16x8*)(xin + s0 * 128 + c8);
    bf16x8 v1 = *(const bf16x8*)(xin + s1 * 128 + c8);
#pragma unroll
    for (int j = 0; j < 8; j++) a[j] += m0 * (float)v0[j] + m1 * (float)v1[j];
  }
#pragma unroll
  for (int j = 0; j < 8; j++) {
    a[j] += __shfl_xor(a[j], 16);
    a[j] += __shfl_xor(a[j], 32);
  }
  if (sub == 0) {
    float inv = 1.0f / fmaxf((float)(e1 - e0), 1.0f);
    bf16x8 o;
#pragma unroll
    for (int j = 0; j < 8; j++) o[j] = (bf16)(a[j] * inv);
    *(bf16x8*)(aggout + wid * 128 + c8) = o;
  }
}

// ---------------- fused [agg|prev] @ [wl;wr] + b, ReLU, (+prev), LayerNorm ----------------
// Block = 256 thr (4 waves); block covers 256 rows, wave 64 rows (4 row-tiles of 16).
// Weights f32 in HBM, staged once per block as bf16 B^T (64KB LDS, K=256 fused [wl;wr]).
// MFMA 16x16x32: A[m=lane&15][k=q*8+j]; B[k=q*8+j][n=lane&15]; C/D col=lane&15, row=q*4+reg.
template <typename TO>
__global__ __launch_bounds__(256, 1) void gemm_k(
    const bf16* __restrict__ aggp, const bf16* __restrict__ prev,
    const float* __restrict__ wl, const float* __restrict__ wr,
    const float* __restrict__ bias, const float* __restrict__ gamma,
    const float* __restrict__ beta, TO* __restrict__ outp, int addres) {
  __shared__ bf16 bt[128 * 256];
  int tid = threadIdx.x;
  for (int e = tid; e < 128 * 64; e += 256) {
    int k  = e >> 6;
    int n2 = (e & 63) << 1;
    {
      float2 v = *(const float2*)(wl + k * 128 + n2);
      bt[swz(n2, k)]     = (bf16)v.x;
      bt[swz(n2 + 1, k)] = (bf16)v.y;
    }
    {
      float2 v = *(const float2*)(wr + k * 128 + n2);
      bt[swz(n2, k + 128)]     = (bf16)v.x;
      bt[swz(n2 + 1, k + 128)] = (bf16)v.y;
    }
  }
  __syncthreads();

  int wave = tid >> 6, lane = tid & 63;
  int q = lane >> 4, r = lane & 15;
  int wrow = blockIdx.x * 256 + wave * 64;

  int arow[4];
#pragma unroll
  for (int rt = 0; rt < 4; rt++) {
    int ar = wrow + rt * 16 + r;
    arow[rt] = (ar < NND) ? ar : (NND - 1);  // clamped; OOB rows never stored
  }

  f32x4 acc[4][8] = {};

#pragma unroll
  for (int kk = 0; kk < 8; kk++) {
    int kof = kk * 32 + q * 8;
    bf16x8 af[4];
#pragma unroll
    for (int rt = 0; rt < 4; rt++) {
      const bf16* ap = (kk < 4) ? (aggp + arow[rt] * 128 + kof)
                                : (prev + arow[rt] * 128 + (kof - 128));
      af[rt] = *(const bf16x8*)ap;
    }
#pragma unroll
    for (int t = 0; t < 8; t++) {
      int n = t * 16 + r;
      bf16x8 bfrag = *(const bf16x8*)&bt[n * 256 + (((kof >> 3) ^ (n & 31)) << 3)];
#pragma unroll
      for (int rt = 0; rt < 4; rt++)
        acc[rt][t] = __builtin_amdgcn_mfma_f32_16x16x32_bf16(af[rt], bfrag, acc[rt][t], 0, 0, 0);
    }
  }

  float biasf[8], gf[8], bef[8];
#pragma unroll
  for (int t = 0; t < 8; t++) {
    int c = t * 16 + r;
    biasf[t] = bias[c];
    gf[t]    = gamma[c];
    bef[t]   = beta[c];
  }

#pragma unroll
  for (int rt = 0; rt < 4; rt++) {
#pragma unroll
    for (int reg = 0; reg < 4; reg++) {
      int row = wrow + rt * 16 + q * 4 + reg;
      int rr  = (row < NND) ? row : (NND - 1);
      const bf16* prow = prev + rr * 128;
      float vals[8];
      float s = 0.f, s2 = 0.f;
#pragma unroll
      for (int t = 0; t < 8; t++) {
        float v = acc[rt][t][reg] + biasf[t];
        v = fmaxf(v, 0.f);
        if (addres) v += (float)prow[t * 16 + r];
        vals[t] = v;
        s += v;
        s2 += v * v;
      }
#pragma unroll
      for (int m = 1; m < 16; m <<= 1) {
        s  += __shfl_xor(s, m);
        s2 += __shfl_xor(s2, m);
      }
      float mean = s * (1.f / 128.f);
      float var  = fmaxf(s2 * (1.f / 128.f) - mean * mean, 0.f);
      float rstd = rsqrtf(var + 1e-5f);
      if (row < NND) {
        TO* orow = outp + row * 128;
#pragma unroll
        for (int t = 0; t < 8; t++)
          orow[t * 16 + r] = (TO)((vals[t] - mean) * rstd * gf[t] + bef[t]);
      }
    }
  }
}

// ---------------- fused mean-pool + head (sorted batch, no atomics) ----------------
__global__ __launch_bounds__(256) void poolhead_k(
    const float* __restrict__ h3, const int* __restrict__ gs,
    const float* __restrict__ wc, const float* __restrict__ bc,
    float* __restrict__ outv, float* __restrict__ avgv) {
  int g = blockIdx.x;
  int s = gs[g], epos = gs[g + 1];
  int tid = threadIdx.x;
  int wave = tid >> 6, lane = tid & 63;
  float a0 = 0.f, a1 = 0.f;
  for (int row = s + wave; row < epos; row += 4) {
    float2 v = *(const float2*)(h3 + row * 128 + 2 * lane);
    a0 += v.x; a1 += v.y;
  }
  __shared__ float red[4][128];
  red[wave][2 * lane]     = a0;
  red[wave][2 * lane + 1] = a1;
  __syncthreads();
  __shared__ float sp[4];
  if (tid < 128) {
    float t4  = red[0][tid] + red[1][tid] + red[2][tid] + red[3][tid];
    float inv = 1.f / fmaxf((float)(epos - s), 1.f);
    float avg = t4 * inv;
    avgv[g * 128 + tid] = avg;
    float p0 = avg * wc[tid * 2 + 0];
    float p1 = avg * wc[tid * 2 + 1];
#pragma unroll
    for (int m = 1; m < 64; m <<= 1) {
      p0 += __shfl_xor(p0, m);
      p1 += __shfl_xor(p1, m);
    }
    if ((tid & 63) == 0) {
      sp[(tid >> 6) * 2]     = p0;
      sp[(tid >> 6) * 2 + 1] = p1;
    }
  }
  __syncthreads();
  if (tid == 0) {
    outv[g * 2 + 0] = sp[0] + sp[2] + bc[0];
    outv[g * 2 + 1] = sp[1] + sp[3] + bc[1];
  }
}

extern "C" void kernel_launch(void* const* d_in, const int* in_sizes, int n_in,
                              void* d_out, int out_size, void* d_ws, size_t ws_size,
                              hipStream_t stream) {
  const float* x   = (const float*)d_in[0];
  const int* ei    = (const int*)d_in[1];
  const int* batch = (const int*)d_in[2];
  const float* w1l = (const float*)d_in[3],  *w1r = (const float*)d_in[4];
  const float* b1  = (const float*)d_in[5],  *g1  = (const float*)d_in[6],  *be1 = (const float*)d_in[7];
  const float* w2l = (const float*)d_in[8],  *w2r = (const float*)d_in[9];
  const float* b2  = (const float*)d_in[10], *g2  = (const float*)d_in[11], *be2 = (const float*)d_in[12];
  const float* w3l = (const float*)d_in[13], *w3r = (const float*)d_in[14];
  const float* b3  = (const float*)d_in[15], *g3  = (const float*)d_in[16], *be3 = (const float*)d_in[17];
  const float* wc  = (const float*)d_in[18], *bc  = (const float*)d_in[19];
  const int* srcv = ei;
  const int* dstv = ei + NE;

  char* base = (char*)d_ws;
  int*  cnt    = (int*)(base + 0);            // 200000  [zeroed]
  int*  cursor = (int*)(base + 200192);       // 200000
  int*  gs     = (int*)(base + 400384);       // 2052
  int*  off    = (int*)(base + 402688);       // 200004
  int*  bsum   = (int*)(base + 602752);       // 512
  int*  csr    = (int*)(base + 603264);       // 3200000
  bf16* agg    = (bf16*)(base + 3803264);     // 12.8 MB
  bf16* h1     = (bf16*)(base + 16603264);    // 12.8 MB
  bf16* h2xb   = (bf16*)(base + 29403264);    // 12.8 MB: xb (x as bf16) until gemm1, then h2

  float* outv = (float*)d_out;             // 1024
  float* h3   = outv + 1024;               // 50000*128
  float* avgv = outv + 1024 + NND * CF;    // 512*128

  hipMemsetAsync(cnt, 0, 200192, stream);
  convcount_k<<<6250, 256, 0, stream>>>(x, h2xb, dstv, cnt);
  scan1_k<<<98, 512, 0, stream>>>(cnt, bsum);
  scan2_k<<<1, 128, 0, stream>>>(bsum, off);
  scan3_k<<<98, 512, 0, stream>>>(cnt, bsum, off, cursor);
  fill_k<<<3125, 256, 0, stream>>>(srcv, dstv, cursor, csr);
  gb_k<<<196, 256, 0, stream>>>(batch, gs);

  // layer 1 (xb aliases h2xb; dead after gemm1 consumes it)
  agg_k<<<12500, 256, 0, stream>>>(h2xb, off, csr, agg);
  gemm_k<bf16><<<196, 256, 0, stream>>>(agg, h2xb, w1l, w1r, b1, g1, be1, h1, 0);
  // layer 2
  agg_k<<<12500, 256, 0, stream>>>(h1, off, csr, agg);
  gemm_k<bf16><<<196, 256, 0, stream>>>(agg, h1, w2l, w2r, b2, g2, be2, h2xb, 1);
  // layer 3
  agg_k<<<12500, 256, 0, stream>>>(h2xb, off, csr, agg);
  gemm_k<float><<<196, 256, 0, stream>>>(agg, h2xb, w3l, w3r, b3, g3, be3, h3, 1);
  // pool + head
  poolhead_k<<<NGR, 256, 0, stream>>>(h3, gs, wc, bc, outv, avgv);
}